// Round 3
// baseline (79.414 us; speedup 1.0000x reference)
//
#include <hip/hip_runtime.h>
#include <math.h>

// TransferNet: BSZ=8, E=40000, D=128, R=512, NUM_STEPS=2, K=3, DEG=64
#define BSZ 8
#define E_ENT 40000
#define D_DIM 128
#define K_TOP 3
#define DEG 64
#define M_TRI (K_TOP * DEG)   // 192
#define D3 (3 * D_DIM)        // 384
#define NCH 40                // chunks per row for dense top-1
#define CHUNK 1000            // NCH * CHUNK == E_ENT
#define EPB 8                 // edges (GRU cells) per block in step kernels
#define G_PER (DEG / EPB)     // 8 edge-groups per picked entity

// prep block-role ranges
#define ZERO_BLOCKS 313                   // ceil(320000/4 /256) float4 stores
#define TR_BLOCKS 192                     // 384*128 / 256
#define CQ_BLOCKS (2 * BSZ)               // 16
#define SA_BLOCKS (BSZ * NCH)             // 320
#define PREP_BLOCKS (ZERO_BLOCKS + TR_BLOCKS + CQ_BLOCKS + SA_BLOCKS)

typedef unsigned long long ull;

__device__ __forceinline__ float sigmoidf_(float x) { return 1.0f / (1.0f + expf(-x)); }

// Key preserves jax.lax.top_k order for v >= 0: value desc, tie -> lower index.
__device__ __forceinline__ ull make_key(float v, int idx) {
    return ((ull)__float_as_uint(v) << 32) |
           (ull)(0xFFFFFFFFu - (unsigned int)idx);
}
__device__ __forceinline__ int key_idx(ull k) {
    return (int)(0xFFFFFFFFu - (unsigned int)(k & 0xFFFFFFFFull));
}
__device__ __forceinline__ float key_val(ull k) {
    return __uint_as_float((unsigned int)(k >> 32));
}

// ---------------------------------------------------------------------------
// prep: zero d_out | transpose GRU weights | cq = tanh(q@W+b) | top-1 stage A
// All four roles are independent; one launch, block-role switch.
// ---------------------------------------------------------------------------
__global__ void prep_kernel(const float* __restrict__ start,
                            const float* __restrict__ rel_emb,
                            const float* __restrict__ step_W,
                            const float* __restrict__ step_b,
                            const int* __restrict__ query,
                            const float* __restrict__ W_ih,
                            const float* __restrict__ W_hh,
                            float* __restrict__ WT_ih,
                            float* __restrict__ WT_hh,
                            float* __restrict__ cq,
                            ull* __restrict__ keysA,
                            float* __restrict__ out) {
    int blk = blockIdx.x, tid = threadIdx.x;
    __shared__ float xs[D_DIM];
    __shared__ ull red[256];
    if (blk < ZERO_BLOCKS) {
        int i = blk * 256 + tid;
        if (i < (BSZ * E_ENT) / 4) ((float4*)out)[i] = float4{0.f, 0.f, 0.f, 0.f};
    } else if (blk < ZERO_BLOCKS + TR_BLOCKS) {
        int i = (blk - ZERO_BLOCKS) * 256 + tid;
        int row = i / D_DIM, col = i % D_DIM;
        WT_ih[col * D3 + row] = W_ih[row * D_DIM + col];
        WT_hh[col * D3 + row] = W_hh[row * D_DIM + col];
    } else if (blk < ZERO_BLOCKS + TR_BLOCKS + CQ_BLOCKS) {
        int g = blk - (ZERO_BLOCKS + TR_BLOCKS);
        int t = g / BSZ, b = g % BSZ;
        if (tid < D_DIM) xs[tid] = rel_emb[query[b] * D_DIM + tid];
        __syncthreads();
        if (tid < D_DIM) {
            float acc = step_b[t * D_DIM + tid];
            const float* W = step_W + t * D_DIM * D_DIM;
            for (int k = 0; k < D_DIM; k++) acc += xs[k] * W[k * D_DIM + tid];
            cq[(t * BSZ + b) * D_DIM + tid] = tanhf(acc);
        }
    } else {
        int g = blk - (ZERO_BLOCKS + TR_BLOCKS + CQ_BLOCKS);
        int b = g / NCH, c = g % NCH;
        const float* row = start + (size_t)b * E_ENT;
        int base = c * CHUNK;
        ull best = 0ull;
        for (int i = tid; i < CHUNK; i += 256) {
            int idx = base + i;
            ull k = make_key(row[idx], idx);
            if (k > best) best = k;
        }
        red[tid] = best;
        __syncthreads();
        for (int s = 128; s > 0; s >>= 1) {
            if (tid < s && red[tid + s] > red[tid]) red[tid] = red[tid + s];
            __syncthreads();
        }
        if (tid == 0) keysA[b * NCH + c] = red[0];
    }
}

// ---------------------------------------------------------------------------
// step0: fused stage-B top-1 reduce + 8 GRU cells per block (h == 0).
// Emits sparse records: feat = trans*obj_p, obj, p.  64 blocks x 128 thr.
// ---------------------------------------------------------------------------
__global__ __launch_bounds__(128) void step0_kernel(
        const ull* __restrict__ keysA,
        const float* __restrict__ cq,        // t=0 slice [BSZ][D]
        const float* __restrict__ rel_emb,
        const int* __restrict__ kb_triple,
        const int* __restrict__ kb_range,
        const float* __restrict__ WT_ih,
        const float* __restrict__ b_ih,
        const float* __restrict__ b_hh,
        const float* __restrict__ cls_w,
        const float* __restrict__ cls_b,
        float* __restrict__ feat_out,
        int* __restrict__ obj_out,
        float* __restrict__ p_out) {
    int blk = blockIdx.x;
    int b = blk / G_PER, g = blk % G_PER;
    int d = threadIdx.x;  // 128

    __shared__ ull red[64];
    __shared__ float xs[EPB][D_DIM];
    __shared__ float part[EPB][2];
    __shared__ float probs[EPB];

    if (d < 64) red[d] = (d < NCH) ? keysA[b * NCH + d] : 0ull;
    __syncthreads();
    for (int s = 32; s > 0; s >>= 1) {
        if (d < s && red[d + s] > red[d]) red[d] = red[d + s];
        __syncthreads();
    }
    int ent = key_idx(red[0]);
    float sub_p = key_val(red[0]);
    int lo = kb_range[2 * ent], hi = kb_range[2 * ent + 1];

    int objl[EPB]; bool vj[EPB];
    for (int e = 0; e < EPB; e++) {
        int j = g * EPB + e, tri = lo + j;
        vj[e] = tri < hi;
        int tuse = vj[e] ? tri : 0;
        objl[e] = kb_triple[3 * tuse + 1];
        int rel = kb_triple[3 * tuse + 2];
        xs[e][d] = rel_emb[rel * D_DIM + d];
    }
    __syncthreads();

    float bhr = b_hh[d], bhz = b_hh[D_DIM + d], bhn = b_hh[2 * D_DIM + d];
    float ir[EPB], iz[EPB], inn[EPB];
    {
        float bir = b_ih[d], biz = b_ih[D_DIM + d], bin = b_ih[2 * D_DIM + d];
        for (int e = 0; e < EPB; e++) { ir[e] = bir; iz[e] = biz; inn[e] = bin; }
    }
    for (int kk = 0; kk < D_DIM; kk++) {
        const float* wi = WT_ih + kk * D3;
        float wr = wi[d], wz = wi[D_DIM + d], wn = wi[2 * D_DIM + d];
        #pragma unroll
        for (int e = 0; e < EPB; e++) {
            float xk = xs[e][kk];
            ir[e] += xk * wr; iz[e] += xk * wz; inn[e] += xk * wn;
        }
    }
    float cqd = cq[b * D_DIM + d] * cls_w[d];
    float trans[EPB];
    for (int e = 0; e < EPB; e++) {
        float r = sigmoidf_(ir[e] + bhr);
        float z = sigmoidf_(iz[e] + bhz);
        float n = tanhf(inn[e] + r * bhn);
        trans[e] = (1.f - z) * n;  // h == 0 at step 0
        float v = trans[e] * cqd;
        for (int off = 32; off > 0; off >>= 1) v += __shfl_xor(v, off, 64);
        if ((d & 63) == 0) part[e][d >> 6] = v;
    }
    __syncthreads();
    if (d < EPB) probs[d] = sigmoidf_(part[d][0] + part[d][1] + cls_b[0]);
    __syncthreads();
    for (int e = 0; e < EPB; e++) {
        int j = g * EPB + e;
        float obj_p = vj[e] ? sub_p * probs[e] : 0.f;
        feat_out[((size_t)b * DEG + j) * D_DIM + d] = trans[e] * obj_p;
        if (d == 0) { obj_out[b * DEG + j] = objl[e]; p_out[b * DEG + j] = obj_p; }
    }
}

// ---------------------------------------------------------------------------
// step1: fused candidate top-3 (over step-0's 64 records, aggregated +
// normalized) + 8 GRU cells per block with hist lookup.  192 blocks x 128.
// Emits (obj, p) records for finalize.  No atomics, no dense writes.
// ---------------------------------------------------------------------------
__global__ __launch_bounds__(128) void step1_kernel(
        const int* __restrict__ objs,
        const float* __restrict__ p0,
        const float* __restrict__ feat_in,
        const float* __restrict__ cq,        // t=1 slice [BSZ][D]
        const float* __restrict__ rel_emb,
        const int* __restrict__ kb_triple,
        const int* __restrict__ kb_range,
        const float* __restrict__ WT_ih,
        const float* __restrict__ WT_hh,
        const float* __restrict__ b_ih,
        const float* __restrict__ b_hh,
        const float* __restrict__ cls_w,
        const float* __restrict__ cls_b,
        int* __restrict__ obj_out,
        float* __restrict__ p_out) {
    int blk = blockIdx.x;
    int b = blk / (K_TOP * G_PER);
    int rem = blk % (K_TOP * G_PER);
    int k = rem / G_PER, g = rem % G_PER;
    int d = threadIdx.x;  // 128

    __shared__ int so[DEG];
    __shared__ float sp[DEG];
    __shared__ ull red[64];
    __shared__ int pick_i[K_TOP];
    __shared__ float pick_v[K_TOP];
    __shared__ float hds[D_DIM];
    __shared__ float xs[EPB][D_DIM];
    __shared__ float part[EPB][2];
    __shared__ float probs[EPB];

    if (d < DEG) { so[d] = objs[b * DEG + d]; sp[d] = p0[b * DEG + d]; }
    __syncthreads();

    // candidate top-3: aggregate duplicates, normalize by max(v,1), 3-pass
    ull mykey = 0ull; int myobj = -1;
    if (d < DEG) {
        myobj = so[d];
        float v = 0.f;
        for (int i = 0; i < DEG; i++) if (so[i] == myobj) v += sp[i];
        v = v / fmaxf(v, 1.f);
        mykey = make_key(v, myobj);
    }
    for (int p = 0; p < K_TOP; p++) {
        ull k2 = mykey;
        for (int q = 0; q < p; q++) if (myobj == pick_i[q]) k2 = 0ull;
        if (d < 64) red[d] = k2;
        __syncthreads();
        for (int s = 32; s > 0; s >>= 1) {
            if (d < s && red[d + s] > red[d]) red[d] = red[d + s];
            __syncthreads();
        }
        if (d == 0) {
            int idx = key_idx(red[0]);
            float val = key_val(red[0]);
            if (idx < 0 || idx >= E_ENT) { idx = p; val = 0.f; }  // <3 positives guard
            pick_i[p] = idx; pick_v[p] = val;
        }
        __syncthreads();
    }
    int ent = pick_i[k];
    float sub_p = pick_v[k];

    // hist[b, ent] (sub == ent for valid KB edges): match-and-sum records
    float hd = 0.f;
    for (int m = 0; m < DEG; m++)
        if (so[m] == ent) hd += feat_in[((size_t)b * DEG + m) * D_DIM + d];
    hds[d] = hd;

    int lo = kb_range[2 * ent], hi = kb_range[2 * ent + 1];
    int objl[EPB]; bool vj[EPB];
    for (int e = 0; e < EPB; e++) {
        int j = g * EPB + e, tri = lo + j;
        vj[e] = tri < hi;
        int tuse = vj[e] ? tri : 0;
        objl[e] = kb_triple[3 * tuse + 1];
        int rel = kb_triple[3 * tuse + 2];
        xs[e][d] = rel_emb[rel * D_DIM + d];
    }
    __syncthreads();

    float hr = b_hh[d], hz = b_hh[D_DIM + d], hn = b_hh[2 * D_DIM + d];
    float ir[EPB], iz[EPB], inn[EPB];
    {
        float bir = b_ih[d], biz = b_ih[D_DIM + d], bin = b_ih[2 * D_DIM + d];
        for (int e = 0; e < EPB; e++) { ir[e] = bir; iz[e] = biz; inn[e] = bin; }
    }
    for (int kk = 0; kk < D_DIM; kk++) {
        const float* wi = WT_ih + kk * D3;
        const float* wh = WT_hh + kk * D3;
        float wr = wi[d], wz = wi[D_DIM + d], wn = wi[2 * D_DIM + d];
        float hk = hds[kk];
        hr += hk * wh[d]; hz += hk * wh[D_DIM + d]; hn += hk * wh[2 * D_DIM + d];
        #pragma unroll
        for (int e = 0; e < EPB; e++) {
            float xk = xs[e][kk];
            ir[e] += xk * wr; iz[e] += xk * wz; inn[e] += xk * wn;
        }
    }
    float cqd = cq[b * D_DIM + d] * cls_w[d];
    for (int e = 0; e < EPB; e++) {
        float r = sigmoidf_(ir[e] + hr);
        float z = sigmoidf_(iz[e] + hz);
        float n = tanhf(inn[e] + r * hn);
        float trans = (1.f - z) * n + z * hd;
        float v = trans * cqd;
        for (int off = 32; off > 0; off >>= 1) v += __shfl_xor(v, off, 64);
        if ((d & 63) == 0) part[e][d >> 6] = v;
    }
    __syncthreads();
    if (d < EPB) probs[d] = sigmoidf_(part[d][0] + part[d][1] + cls_b[0]);
    __syncthreads();
    if (d == 0) {
        for (int e = 0; e < EPB; e++) {
            int idx = b * M_TRI + k * DEG + g * EPB + e;
            obj_out[idx] = objl[e];
            p_out[idx] = vj[e] ? sub_p * probs[e] : 0.f;
        }
    }
}

// ---------------------------------------------------------------------------
// finalize: aggregate the 192 (obj, p) records per row, write normalized
// values into the pre-zeroed dense output. Duplicate threads write identical
// values -> deterministic, no atomics.  8 blocks x 192 threads.
// ---------------------------------------------------------------------------
__global__ void finalize_kernel(const int* __restrict__ obj1,
                                const float* __restrict__ p1,
                                float* __restrict__ out) {
    int b = blockIdx.x, m = threadIdx.x;  // 192
    __shared__ int so[M_TRI];
    __shared__ float sp[M_TRI];
    so[m] = obj1[b * M_TRI + m];
    sp[m] = p1[b * M_TRI + m];
    __syncthreads();
    int o = so[m];
    float v = 0.f;
    for (int i = 0; i < M_TRI; i++) if (so[i] == o) v += sp[i];
    out[(size_t)b * E_ENT + o] = v / fmaxf(v, 1.f);
}

extern "C" void kernel_launch(void* const* d_in, const int* in_sizes, int n_in,
                              void* d_out, int out_size, void* d_ws, size_t ws_size,
                              hipStream_t stream) {
    const float* start    = (const float*)d_in[0];
    const float* rel_emb  = (const float*)d_in[1];
    const float* step_W   = (const float*)d_in[2];
    const float* step_b   = (const float*)d_in[3];
    const float* W_ih     = (const float*)d_in[4];
    const float* W_hh     = (const float*)d_in[5];
    const float* b_ih     = (const float*)d_in[6];
    const float* b_hh     = (const float*)d_in[7];
    const float* cls_w    = (const float*)d_in[8];
    const float* cls_b    = (const float*)d_in[9];
    const int*   query    = (const int*)d_in[10];
    const int*   kb_triple = (const int*)d_in[11];
    const int*   kb_range  = (const int*)d_in[12];
    float* out = (float*)d_out;

    char* ws = (char*)d_ws;
    float* WT_ih = (float*)ws;  ws += (size_t)D3 * D_DIM * sizeof(float);
    float* WT_hh = (float*)ws;  ws += (size_t)D3 * D_DIM * sizeof(float);
    float* cq    = (float*)ws;  ws += (size_t)2 * BSZ * D_DIM * sizeof(float);
    float* feat  = (float*)ws;  ws += (size_t)BSZ * DEG * D_DIM * sizeof(float);
    int*   objs  = (int*)ws;    ws += (size_t)BSZ * DEG * sizeof(int);
    float* p0    = (float*)ws;  ws += (size_t)BSZ * DEG * sizeof(float);
    ull*   keysA = (ull*)ws;    ws += (size_t)BSZ * NCH * sizeof(ull);
    int*   obj1  = (int*)ws;    ws += (size_t)BSZ * M_TRI * sizeof(int);
    float* p1    = (float*)ws;  ws += (size_t)BSZ * M_TRI * sizeof(float);

    prep_kernel<<<PREP_BLOCKS, 256, 0, stream>>>(
        start, rel_emb, step_W, step_b, query, W_ih, W_hh,
        WT_ih, WT_hh, cq, keysA, out);

    step0_kernel<<<BSZ * G_PER, 128, 0, stream>>>(
        keysA, cq, rel_emb, kb_triple, kb_range,
        WT_ih, b_ih, b_hh, cls_w, cls_b,
        feat, objs, p0);

    step1_kernel<<<BSZ * K_TOP * G_PER, 128, 0, stream>>>(
        objs, p0, feat, cq + BSZ * D_DIM, rel_emb, kb_triple, kb_range,
        WT_ih, WT_hh, b_ih, b_hh, cls_w, cls_b,
        obj1, p1);

    finalize_kernel<<<BSZ, M_TRI, 0, stream>>>(obj1, p1, out);
}

// Round 4
// 60.018 us; speedup vs baseline: 1.3232x; 1.3232x over previous
//
#include <hip/hip_runtime.h>
#include <math.h>

// TransferNet: BSZ=8, E=40000, D=128, R=512, NUM_STEPS=2, K=3, DEG=64
#define BSZ 8
#define E_ENT 40000
#define D_DIM 128
#define K_TOP 3
#define DEG 64
#define M_TRI (K_TOP * DEG)   // 192
#define D3 (3 * D_DIM)        // 384
#define NCH 40                // chunks per row for dense top-1
#define CHUNK 1000            // NCH * CHUNK == E_ENT

// prep block-role ranges
#define ZERO_BLOCKS 313                   // ceil(320000/4 /256) float4 stores
#define TR_BLOCKS 192                     // 384*128 / 256
#define CQ_BLOCKS (2 * BSZ)               // 16
#define SA_BLOCKS (BSZ * NCH)             // 320
#define PREP_BLOCKS (ZERO_BLOCKS + TR_BLOCKS + CQ_BLOCKS + SA_BLOCKS)

typedef unsigned long long ull;

__device__ __forceinline__ float sigmoidf_(float x) { return 1.0f / (1.0f + expf(-x)); }

// Key preserves jax.lax.top_k order for v >= 0: value desc, tie -> lower index.
__device__ __forceinline__ ull make_key(float v, int idx) {
    return ((ull)__float_as_uint(v) << 32) |
           (ull)(0xFFFFFFFFu - (unsigned int)idx);
}
__device__ __forceinline__ int key_idx(ull k) {
    return (int)(0xFFFFFFFFu - (unsigned int)(k & 0xFFFFFFFFull));
}
__device__ __forceinline__ float key_val(ull k) {
    return __uint_as_float((unsigned int)(k >> 32));
}

// ---------------------------------------------------------------------------
// prep: zero d_out | transpose GRU weights | cq = tanh(q@W+b) | top-1 stage A
// ---------------------------------------------------------------------------
__global__ void prep_kernel(const float* __restrict__ start,
                            const float* __restrict__ rel_emb,
                            const float* __restrict__ step_W,
                            const float* __restrict__ step_b,
                            const int* __restrict__ query,
                            const float* __restrict__ W_ih,
                            const float* __restrict__ W_hh,
                            float* __restrict__ WT_ih,
                            float* __restrict__ WT_hh,
                            float* __restrict__ cq,
                            ull* __restrict__ keysA,
                            float* __restrict__ out) {
    int blk = blockIdx.x, tid = threadIdx.x;
    __shared__ float xs[D_DIM];
    __shared__ ull red[256];
    if (blk < ZERO_BLOCKS) {
        int i = blk * 256 + tid;
        if (i < (BSZ * E_ENT) / 4) ((float4*)out)[i] = float4{0.f, 0.f, 0.f, 0.f};
    } else if (blk < ZERO_BLOCKS + TR_BLOCKS) {
        int i = (blk - ZERO_BLOCKS) * 256 + tid;
        int row = i / D_DIM, col = i % D_DIM;
        WT_ih[col * D3 + row] = W_ih[row * D_DIM + col];
        WT_hh[col * D3 + row] = W_hh[row * D_DIM + col];
    } else if (blk < ZERO_BLOCKS + TR_BLOCKS + CQ_BLOCKS) {
        int g = blk - (ZERO_BLOCKS + TR_BLOCKS);
        int t = g / BSZ, b = g % BSZ;
        if (tid < D_DIM) xs[tid] = rel_emb[query[b] * D_DIM + tid];
        __syncthreads();
        if (tid < D_DIM) {
            float acc = step_b[t * D_DIM + tid];
            const float* W = step_W + t * D_DIM * D_DIM;
            for (int k = 0; k < D_DIM; k++) acc += xs[k] * W[k * D_DIM + tid];
            cq[(t * BSZ + b) * D_DIM + tid] = tanhf(acc);
        }
    } else {
        int g = blk - (ZERO_BLOCKS + TR_BLOCKS + CQ_BLOCKS);
        int b = g / NCH, c = g % NCH;
        const float* row = start + (size_t)b * E_ENT;
        int base = c * CHUNK;
        ull best = 0ull;
        for (int i = tid; i < CHUNK; i += 256) {
            int idx = base + i;
            ull k = make_key(row[idx], idx);
            if (k > best) best = k;
        }
        red[tid] = best;
        __syncthreads();
        for (int s = 128; s > 0; s >>= 1) {
            if (tid < s && red[tid + s] > red[tid]) red[tid] = red[tid + s];
            __syncthreads();
        }
        if (tid == 0) keysA[b * NCH + c] = red[0];
    }
}

// ---------------------------------------------------------------------------
// step0: fused stage-B top-1 reduce + one GRU cell per block (h == 0).
// 512 blocks x 128 threads (12+ waves/CU for latency hiding).
// ---------------------------------------------------------------------------
__global__ __launch_bounds__(128) void step0_kernel(
        const ull* __restrict__ keysA,
        const float* __restrict__ cq,        // t=0 slice [BSZ][D]
        const float* __restrict__ rel_emb,
        const int* __restrict__ kb_triple,
        const int* __restrict__ kb_range,
        const float* __restrict__ WT_ih,
        const float* __restrict__ b_ih,
        const float* __restrict__ b_hh,
        const float* __restrict__ cls_w,
        const float* __restrict__ cls_b,
        float* __restrict__ feat_out,
        int* __restrict__ obj_out,
        float* __restrict__ p_out) {
    int blk = blockIdx.x;
    int b = blk / DEG, j = blk % DEG;
    int d = threadIdx.x;  // 128

    __shared__ ull kred[64];
    __shared__ float xs[D_DIM];
    __shared__ float red[D_DIM];

    if (d < 64) kred[d] = (d < NCH) ? keysA[b * NCH + d] : 0ull;
    __syncthreads();
    for (int s = 32; s > 0; s >>= 1) {
        if (d < s && kred[d + s] > kred[d]) kred[d] = kred[d + s];
        __syncthreads();
    }
    int ent = key_idx(kred[0]);
    float sub_p = key_val(kred[0]);
    int lo = kb_range[2 * ent], hi = kb_range[2 * ent + 1];
    int tri = lo + j;
    bool vj = tri < hi;
    int tuse = vj ? tri : 0;
    int obj = kb_triple[3 * tuse + 1];
    int rel = kb_triple[3 * tuse + 2];

    xs[d] = rel_emb[rel * D_DIM + d];
    __syncthreads();

    float ir = b_ih[d], iz = b_ih[D_DIM + d], inn = b_ih[2 * D_DIM + d];
    for (int kk = 0; kk < D_DIM; kk++) {
        const float* wi = WT_ih + kk * D3;
        float xk = xs[kk];
        ir += xk * wi[d]; iz += xk * wi[D_DIM + d]; inn += xk * wi[2 * D_DIM + d];
    }
    float r = sigmoidf_(ir + b_hh[d]);
    float z = sigmoidf_(iz + b_hh[D_DIM + d]);
    float n = tanhf(inn + r * b_hh[2 * D_DIM + d]);
    float trans = (1.f - z) * n;  // h == 0 at step 0

    red[d] = trans * cq[b * D_DIM + d] * cls_w[d];
    __syncthreads();
    for (int s = 64; s > 0; s >>= 1) {
        if (d < s) red[d] += red[d + s];
        __syncthreads();
    }
    float prob = sigmoidf_(red[0] + cls_b[0]);
    float obj_p = vj ? sub_p * prob : 0.f;

    feat_out[((size_t)b * DEG + j) * D_DIM + d] = trans * obj_p;
    if (d == 0) { obj_out[b * DEG + j] = obj; p_out[b * DEG + j] = obj_p; }
}

// ---------------------------------------------------------------------------
// step1: fused candidate top-3 (aggregate + normalize + 3-pass over 64
// step-0 records) + one GRU cell per block with hist lookup.
// 1536 blocks x 128 threads.  No atomics, no dense writes.
// ---------------------------------------------------------------------------
__global__ __launch_bounds__(128) void step1_kernel(
        const int* __restrict__ objs,
        const float* __restrict__ p0,
        const float* __restrict__ feat_in,
        const float* __restrict__ cq,        // t=1 slice [BSZ][D]
        const float* __restrict__ rel_emb,
        const int* __restrict__ kb_triple,
        const int* __restrict__ kb_range,
        const float* __restrict__ WT_ih,
        const float* __restrict__ WT_hh,
        const float* __restrict__ b_ih,
        const float* __restrict__ b_hh,
        const float* __restrict__ cls_w,
        const float* __restrict__ cls_b,
        int* __restrict__ obj_out,
        float* __restrict__ p_out) {
    int blk = blockIdx.x;
    int b = blk / (K_TOP * DEG);
    int rem = blk % (K_TOP * DEG);
    int k = rem / DEG, j = rem % DEG;
    int d = threadIdx.x;  // 128

    __shared__ int so[DEG];
    __shared__ float sp[DEG];
    __shared__ ull kred[64];
    __shared__ int pick_i[K_TOP];
    __shared__ float pick_v[K_TOP];
    __shared__ float hds[D_DIM];
    __shared__ float xs[D_DIM];
    __shared__ float red[D_DIM];

    if (d < DEG) { so[d] = objs[b * DEG + d]; sp[d] = p0[b * DEG + d]; }
    __syncthreads();

    // candidate top-3: aggregate duplicates (ascending order = jax scatter
    // order), normalize by max(v,1), 3-pass exclusion
    ull mykey = 0ull; int myobj = -1;
    if (d < DEG) {
        myobj = so[d];
        float v = 0.f;
        for (int i = 0; i < DEG; i++) if (so[i] == myobj) v += sp[i];
        v = v / fmaxf(v, 1.f);
        mykey = make_key(v, myobj);
    }
    for (int p = 0; p < K_TOP; p++) {
        ull k2 = mykey;
        for (int q = 0; q < p; q++) if (myobj == pick_i[q]) k2 = 0ull;
        if (d < 64) kred[d] = k2;
        __syncthreads();
        for (int s = 32; s > 0; s >>= 1) {
            if (d < s && kred[d + s] > kred[d]) kred[d] = kred[d + s];
            __syncthreads();
        }
        if (d == 0) {
            int idx = key_idx(kred[0]);
            float val = key_val(kred[0]);
            if (idx < 0 || idx >= E_ENT) { idx = p; val = 0.f; }  // <3 positives guard
            pick_i[p] = idx; pick_v[p] = val;
        }
        __syncthreads();
    }
    int ent = pick_i[k];
    float sub_p = pick_v[k];

    // hist[b, ent]: match-and-sum step-0 records
    float hd = 0.f;
    for (int m = 0; m < DEG; m++)
        if (so[m] == ent) hd += feat_in[((size_t)b * DEG + m) * D_DIM + d];
    hds[d] = hd;

    int lo = kb_range[2 * ent], hi = kb_range[2 * ent + 1];
    int tri = lo + j;
    bool vj = tri < hi;
    int tuse = vj ? tri : 0;
    int obj = kb_triple[3 * tuse + 1];
    int rel = kb_triple[3 * tuse + 2];
    xs[d] = rel_emb[rel * D_DIM + d];
    __syncthreads();

    float ir = b_ih[d], iz = b_ih[D_DIM + d], inn = b_ih[2 * D_DIM + d];
    float hr = b_hh[d], hz = b_hh[D_DIM + d], hn = b_hh[2 * D_DIM + d];
    for (int kk = 0; kk < D_DIM; kk++) {
        const float* wi = WT_ih + kk * D3;
        const float* wh = WT_hh + kk * D3;
        float xk = xs[kk], hk = hds[kk];
        ir += xk * wi[d]; iz += xk * wi[D_DIM + d]; inn += xk * wi[2 * D_DIM + d];
        hr += hk * wh[d]; hz += hk * wh[D_DIM + d]; hn += hk * wh[2 * D_DIM + d];
    }
    float r = sigmoidf_(ir + hr);
    float z = sigmoidf_(iz + hz);
    float n = tanhf(inn + r * hn);
    float trans = (1.f - z) * n + z * hd;

    red[d] = trans * cq[b * D_DIM + d] * cls_w[d];
    __syncthreads();
    for (int s = 64; s > 0; s >>= 1) {
        if (d < s) red[d] += red[d + s];
        __syncthreads();
    }
    float prob = sigmoidf_(red[0] + cls_b[0]);
    if (d == 0) {
        int idx = b * M_TRI + k * DEG + j;
        obj_out[idx] = obj;
        p_out[idx] = vj ? sub_p * prob : 0.f;
    }
}

// ---------------------------------------------------------------------------
// finalize: aggregate the 192 (obj, p) records per row, write normalized
// values into the pre-zeroed dense output. Duplicate threads write identical
// values -> deterministic, no atomics.  8 blocks x 192 threads.
// ---------------------------------------------------------------------------
__global__ void finalize_kernel(const int* __restrict__ obj1,
                                const float* __restrict__ p1,
                                float* __restrict__ out) {
    int b = blockIdx.x, m = threadIdx.x;  // 192
    __shared__ int so[M_TRI];
    __shared__ float sp[M_TRI];
    so[m] = obj1[b * M_TRI + m];
    sp[m] = p1[b * M_TRI + m];
    __syncthreads();
    int o = so[m];
    float v = 0.f;
    for (int i = 0; i < M_TRI; i++) if (so[i] == o) v += sp[i];
    out[(size_t)b * E_ENT + o] = v / fmaxf(v, 1.f);
}

extern "C" void kernel_launch(void* const* d_in, const int* in_sizes, int n_in,
                              void* d_out, int out_size, void* d_ws, size_t ws_size,
                              hipStream_t stream) {
    const float* start    = (const float*)d_in[0];
    const float* rel_emb  = (const float*)d_in[1];
    const float* step_W   = (const float*)d_in[2];
    const float* step_b   = (const float*)d_in[3];
    const float* W_ih     = (const float*)d_in[4];
    const float* W_hh     = (const float*)d_in[5];
    const float* b_ih     = (const float*)d_in[6];
    const float* b_hh     = (const float*)d_in[7];
    const float* cls_w    = (const float*)d_in[8];
    const float* cls_b    = (const float*)d_in[9];
    const int*   query    = (const int*)d_in[10];
    const int*   kb_triple = (const int*)d_in[11];
    const int*   kb_range  = (const int*)d_in[12];
    float* out = (float*)d_out;

    char* ws = (char*)d_ws;
    float* WT_ih = (float*)ws;  ws += (size_t)D3 * D_DIM * sizeof(float);
    float* WT_hh = (float*)ws;  ws += (size_t)D3 * D_DIM * sizeof(float);
    float* cq    = (float*)ws;  ws += (size_t)2 * BSZ * D_DIM * sizeof(float);
    float* feat  = (float*)ws;  ws += (size_t)BSZ * DEG * D_DIM * sizeof(float);
    int*   objs  = (int*)ws;    ws += (size_t)BSZ * DEG * sizeof(int);
    float* p0    = (float*)ws;  ws += (size_t)BSZ * DEG * sizeof(float);
    ull*   keysA = (ull*)ws;    ws += (size_t)BSZ * NCH * sizeof(ull);
    int*   obj1  = (int*)ws;    ws += (size_t)BSZ * M_TRI * sizeof(int);
    float* p1    = (float*)ws;  ws += (size_t)BSZ * M_TRI * sizeof(float);

    prep_kernel<<<PREP_BLOCKS, 256, 0, stream>>>(
        start, rel_emb, step_W, step_b, query, W_ih, W_hh,
        WT_ih, WT_hh, cq, keysA, out);

    step0_kernel<<<BSZ * DEG, 128, 0, stream>>>(
        keysA, cq, rel_emb, kb_triple, kb_range,
        WT_ih, b_ih, b_hh, cls_w, cls_b,
        feat, objs, p0);

    step1_kernel<<<BSZ * K_TOP * DEG, 128, 0, stream>>>(
        objs, p0, feat, cq + BSZ * D_DIM, rel_emb, kb_triple, kb_range,
        WT_ih, WT_hh, b_ih, b_hh, cls_w, cls_b,
        obj1, p1);

    finalize_kernel<<<BSZ, M_TRI, 0, stream>>>(obj1, p1, out);
}